// Round 3
// baseline (254.161 us; speedup 1.0000x reference)
//
#include <hip/hip_runtime.h>
#include <hip/hip_bf16.h>

typedef short s16x8 __attribute__((ext_vector_type(8)));
typedef short s16x4 __attribute__((ext_vector_type(4)));
typedef float f32x4 __attribute__((ext_vector_type(4)));

#define TB 8            // batch elements per group
#define NBG 16          // groups per block; grid 512 = exactly 2 blocks/CU
#define WAVES 6         // 384 threads -> 12 waves/CU at 2 blocks/CU (3 waves/SIMD)
#define NTHREADS (WAVES * 64)
#define HALO 46         // gtile positions per batch (pos -2 .. 43)
#define GSTRIDE 2216    // shorts per batch in gtile (8*odd: bank-decorrelated)
#define USTRIDE 50      // floats per batch in u_s halo (wrap-extended, 50 needed: h<=45, +4 taps)
#define NT 3            // stage-2 N tiles (48 cols, >=37 zero-padded; k=240 = b2 row)
#define GT_SHORTS (TB * GSTRIDE)       // 17728 shorts = 35456 B per buffer

__device__ __forceinline__ unsigned short f2bf(float f) {
    unsigned int u = __float_as_uint(f);
    u += 0x7fff + ((u >> 16) & 1);   // RNE
    return (unsigned short)(u >> 16);
}

// packed f32x2 -> bf16x2 (v_cvt_pk_bf16_f32, RNE)
__device__ __forceinline__ unsigned int pk_bf16(float lo, float hi) {
    float2 f; f.x = lo; f.y = hi;
    __hip_bfloat162 h = __float22bfloat162_rn(f);
    union { __hip_bfloat162 b; unsigned int u; } c;
    c.b = h;
    return c.u;
}

// force a uniform value into SGPR
__device__ __forceinline__ float sload(const float* p) {
    return __uint_as_float(__builtin_amdgcn_readfirstlane(__float_as_uint(*p)));
}

// (384,3): 6-wave blocks, 2 blocks/CU -> 3 waves/SIMD (was 2). Register diet to fit the
// 170-combined cap WITHOUT R1's failure modes: aW2 nt0/1 resident (64 AGPR); nt=2 is
// mostly zeros (rows 37..47) -> compact 2.6KB LDS (W2sz) streamed per-ks (base+ks*step,
// no prefetch chain); bg in halves of 4; W3 via LDS table; pv_4 dropped (quad-store map).
// Double-buffer schedule identical to R2 (no extra barriers).
// Guards: WRITE_SIZE == 10.24 MB (spill -> 90MB+), LDS ~76.9KB.
__global__ __launch_bounds__(NTHREADS, 3) void lorenz96_fused(
    const float* __restrict__ u,
    const float* __restrict__ coeff,
    const float* __restrict__ W1,
    const float* __restrict__ b1,
    const float* __restrict__ W2,
    const float* __restrict__ b2,
    const float* __restrict__ W3,
    const float* __restrict__ b3,
    float* __restrict__ out)
{
    // LDS: gtile 2x35456 (buf0 aliases W2 nt0/1 staging) + u_sbuf 3200 + W2sz 2576 + W3l 192
    //    = 76880 B -> 2 blocks/CU (153.8KB < 160KB)
    __shared__ __align__(16) unsigned short gtile[2][GT_SHORTS];
    __shared__ __align__(16) float u_sbuf[2][TB * USTRIDE];   // u_s[b][k] = u[b][(k+36)%40]
    __shared__ __align__(16) unsigned short W2sz[8 * 4 * 5 * 8 + 8];  // nt2 compact + 16B zero blk
    __shared__ __align__(16) float W3l[48];

    unsigned short* B_lds = &gtile[0][0];   // alias: consumed into regs before gtile[0] is written

    const int t    = threadIdx.x;
    const int lane = t & 63;
    const int wave = t >> 6;                 // 0..5
    const int quad = lane >> 4;
    const int l15  = lane & 15;

    const int b0_block = blockIdx.x * (TB * NBG);

    // ---------- init 0a: W2 staging, pre-swizzled; k=240 carries b2 (bias row, B supplies 1.0) ----------
    // W2eff[o][k = tap*48 + c] = W2[o][c][tap]; lane holds [o = nt*16+l15][k = ks*32+quad*8+j]
    // nt 0,1 -> gtile alias (register-resident); nt 2 -> compact W2sz (only rows o=32..36 nonzero)
    for (int g = t; g < NT * 8 * 64; g += NTHREADS) {
        int lg = g & 63;
        int ks = (g >> 6) & 7;
        int nt = g >> 9;
        int o  = nt * 16 + (lg & 15);
        int kb = ks * 32 + (lg >> 4) * 8;
        s16x8 pack = {0, 0, 0, 0, 0, 0, 0, 0};
        #pragma unroll
        for (int j = 0; j < 8; ++j) {
            int k = kb + j;
            if (o < 37) {
                if (k < 240) {
                    int c = k % 48, tap = k / 48;
                    pack[j] = (short)f2bf(W2[o * 240 + c * 5 + tap]);
                } else if (k == 240) {
                    pack[j] = (short)f2bf(b2[o]);
                }
            }
        }
        if (nt < 2) {
            *(s16x8*)&B_lds[g * 8] = pack;
        } else if ((lg & 15) < 5) {
            *(s16x8*)&W2sz[((ks * 4 + (lg >> 4)) * 5 + (lg & 15)) * 8] = pack;
        }
    }
    if (t < 8)  W2sz[1280 + t] = 0;                     // shared zero block (lanes l15>=5)
    if (t < 48) W3l[t] = (t < 37) ? W3[t] : 0.f;

    // ---------- init 0b: conv1 A-fragments (W1 + fused b1 at k=5) ----------
    // tiles: T0=ch0-15, T1=ch16-31, T2=ch32-47, T3 rows8-15=ch48-55, T4=ch56-71.
    // GLU in-lane: T1 rows8-15 x T3 rows8-15; T2 x T4 (same quad,reg).
    s16x8 aW1[5];
    {
        int chs[5];
        chs[0] = l15; chs[1] = 16 + l15; chs[2] = 32 + l15;
        chs[3] = (l15 >= 8) ? 40 + l15 : -1;
        chs[4] = 56 + l15;
        #pragma unroll
        for (int mt = 0; mt < 5; ++mt) {
            s16x8 a = {0, 0, 0, 0, 0, 0, 0, 0};
            int ch = chs[mt];
            if (quad == 0 && ch >= 0) {
                #pragma unroll
                for (int j = 0; j < 5; ++j) a[j] = (short)f2bf(W1[ch * 5 + j]);
                a[5] = (short)f2bf(b1[ch]);   // bias slot; B supplies 1.0 at k=5
            }
            aW1[mt] = a;
        }
    }

    // ---------- init 0c: epilogue constants ----------
    const float b3v = sload(b3);
    float cf[18];
    #pragma unroll
    for (int i = 0; i < 18; ++i) cf[i] = sload(&coeff[i]);   // SGPR-resident

    // stage-2 A-fragments nt 0/1 only (nt=2 streamed from W2sz)
    s16x8 aW2[2][8];
    // poly term register: pv_q = row of M-tile (wave + 6*quad); clamped for invalid slots
    float pv_q = 0.f;
    const int mtqc = min(wave + WAVES * quad, 19);       // poly row tile for this lane's quad
    // nt2 stream addressing: real rows (l15<5) walk ks*160 shorts; zero lanes pin to zero blk
    const int a2idx  = (l15 < 5) ? (quad * 5 + l15) * 8 : 1280;
    const int a2step = (l15 < 5) ? 160 : 0;
    // T14 staging registers (static-indexed -> stay in VGPRs)
    float st_v0 = 0.f, st_v1 = 0.f;

    // phase2 load-balanced col map: waves with 4 p3-tiles (0,1) get 3 cols; wave5 gets 5.
    // cols: w0:{0..2} w1:{3..5} w2:{6..9} w3:{10..13} w4:{14..17} w5:{18..22}
    const int c_start = (wave < 2) ? wave * 3 : wave * 4 - 2;
    const int c_cnt   = (wave < 2) ? 3 : ((wave == 5) ? 5 : 4);

    // ---------- helpers ----------
    auto prestage_u = [&](int grp) {   // prologue-only: full stage of group grp into u_sbuf[grp&1]
        for (int idx = t; idx < TB * USTRIDE; idx += NTHREADS) {
            int b = idx / USTRIDE, k = idx - b * USTRIDE;
            int gi = k + 36; gi -= (gi >= 40) ? 40 : 0; gi -= (gi >= 40) ? 40 : 0;
            u_sbuf[grp & 1][idx] = u[(size_t)(b0_block + grp * TB + b) * 40 + gi];
        }
    };

    auto prestage_issue = [&](int grp) {   // T14 part 1: issue global loads into regs
        {
            int idx = t;                                   // t < 384 < 400 always
            int b = idx / USTRIDE, k = idx - b * USTRIDE;
            int gi = k + 36; gi -= (gi >= 40) ? 40 : 0; gi -= (gi >= 40) ? 40 : 0;
            st_v0 = u[(size_t)(b0_block + grp * TB + b) * 40 + gi];
        }
        if (t + NTHREADS < TB * USTRIDE) {                 // t < 16
            int idx = t + NTHREADS;
            int b = idx / USTRIDE, k = idx - b * USTRIDE;
            int gi = k + 36; gi -= (gi >= 40) ? 40 : 0; gi -= (gi >= 40) ? 40 : 0;
            st_v1 = u[(size_t)(b0_block + grp * TB + b) * 40 + gi];
        }
    };

    auto prestage_commit = [&](int grp) {  // T14 part 2: LDS writes (just before barrier)
        u_sbuf[grp & 1][t] = st_v0;
        if (t + NTHREADS < TB * USTRIDE) u_sbuf[grp & 1][t + NTHREADS] = st_v1;
    };

    auto poly1 = [&](const float* u_s, int m) -> float {   // poly term for output row m
        int p = m >> 3, b = m & 7;
        const float* us = &u_s[b * USTRIDE + p];
        float um2 = us[2], um1 = us[3], u0 = us[4], up1 = us[5], up2 = us[6];
        return cf[0] + cf[1]*um2 + cf[2]*um1 + cf[3]*u0 + cf[4]*up1 + cf[5]*up2
             + cf[6]*um2*um2 + cf[7]*um1*um1 + cf[8]*u0*u0 + cf[9]*up1*up1 + cf[10]*up2*up2
             + cf[11]*um2*um1 + cf[12]*um1*u0 + cf[13]*u0*up1 + cf[14]*up1*up2
             + cf[15]*um2*u0 + cf[16]*um1*up1 + cf[17]*u0*up2;
    };

    auto phase2 = [&](int gi) {       // conv1 via MFMA + GLU -> gtile[gi&1]
        const float* u_s = u_sbuf[gi & 1];
        unsigned short* gt = &gtile[gi & 1][0];
        #pragma unroll
        for (int ii = 0; ii < 5; ++ii) {
            if (ii >= c_cnt) continue;                  // wave-uniform guard
            const int ct = c_start + ii;                // col-tiles 0..22 (cols 0..367)
            const int col = ct * 16 + l15;
            const int b = col & 7, h = col >> 3;        // h <= 45 < HALO always
            s16x8 bU = {0, 0, 0, 0, 0, 0, 0, 0};
            if (quad == 0) {                            // exec-masked: only 16 lanes touch LDS
                const float* us = &u_s[b * USTRIDE + h];   // taps u[(h-4+j)%40], j=0..4
                union { s16x8 v; unsigned int w[4]; } bu;
                bu.w[0] = pk_bf16(us[0], us[1]);
                bu.w[1] = pk_bf16(us[2], us[3]);
                bu.w[2] = pk_bf16(us[4], 1.0f);            // 1.0 -> bias slot k=5
                bu.w[3] = 0;
                bU = bu.v;
            }
            f32x4 a0 = {0.f,0.f,0.f,0.f}, a1 = a0, a2 = a0, a3 = a0, a4 = a0;
            a0 = __builtin_amdgcn_mfma_f32_16x16x32_bf16(aW1[0], bU, a0, 0, 0, 0);
            a1 = __builtin_amdgcn_mfma_f32_16x16x32_bf16(aW1[1], bU, a1, 0, 0, 0);
            a2 = __builtin_amdgcn_mfma_f32_16x16x32_bf16(aW1[2], bU, a2, 0, 0, 0);
            a3 = __builtin_amdgcn_mfma_f32_16x16x32_bf16(aW1[3], bU, a3, 0, 0, 0);
            a4 = __builtin_amdgcn_mfma_f32_16x16x32_bf16(aW1[4], bU, a4, 0, 0, 0);
            float v0[4], v1[4], v2[4];
            #pragma unroll
            for (int r = 0; r < 4; ++r) {
                v0[r] = fmaxf(a0[r], 0.f);
                v1[r] = fmaxf(a1[r], 0.f);
                if (quad >= 2) v1[r] *= fmaxf(a3[r], 0.f);          // ch24-31 gate
                v2[r] = fmaxf(a2[r], 0.f) * fmaxf(a4[r], 0.f);      // ch32-47 gate
            }
            union { s16x4 v; unsigned int w[2]; } w0, w1, w2;
            w0.w[0] = pk_bf16(v0[0], v0[1]); w0.w[1] = pk_bf16(v0[2], v0[3]);
            w1.w[0] = pk_bf16(v1[0], v1[1]); w1.w[1] = pk_bf16(v1[2], v1[3]);
            w2.w[0] = pk_bf16(v2[0], v2[1]); w2.w[1] = pk_bf16(v2[2], v2[3]);
            unsigned short* gp = &gt[b * GSTRIDE + h * 48 + quad * 4];
            *(s16x4*)(gp)      = w0.v;
            *(s16x4*)(gp + 16) = w1.v;
            *(s16x4*)(gp + 32) = w2.v;
        }
    };

    // P3 tile i: stage-2 GEMM on M-tile (wave+6i) + fused relu/W3 epilogue -> out.
    // bg in halves of 4; nt2 A-frag streamed from W2sz (zero lanes read the zero block).
    auto p3_tile = [&](int i, const unsigned short* gt, int b0) {
        const int mt = wave + WAVES * i;            // 20 M-tiles (320 G-rows)
        const int m  = mt * 16 + l15;
        const int p  = m >> 3, b = m & 7;
        const unsigned short* gbase = &gt[b * GSTRIDE + p * 48 + quad * 8];
        f32x4 c0 = {0.f,0.f,0.f,0.f}, c1 = c0, c2 = c0;
        #pragma unroll
        for (int half = 0; half < 2; ++half) {
            s16x8 bg[4];
            #pragma unroll
            for (int j = 0; j < 4; ++j) bg[j] = *(const s16x8*)(gbase + (half * 4 + j) * 32);
            if (half == 1) {   // bias row: B[k=240][*] must read 1.0 (ks=7, quad=2, j=0)
                s16x8 b7 = bg[3];
                if (quad == 2) b7[0] = (short)0x3F80;
                bg[3] = b7;
            }
            #pragma unroll
            for (int j = 0; j < 4; ++j) {
                const int ks = half * 4 + j;
                s16x8 a2 = *(const s16x8*)&W2sz[a2idx + ks * a2step];
                c0 = __builtin_amdgcn_mfma_f32_16x16x32_bf16(aW2[0][ks], bg[j], c0, 0, 0, 0);
                c1 = __builtin_amdgcn_mfma_f32_16x16x32_bf16(aW2[1][ks], bg[j], c1, 0, 0, 0);
                c2 = __builtin_amdgcn_mfma_f32_16x16x32_bf16(a2,         bg[j], c2, 0, 0, 0);
            }
        }
        float s = 0.f;
        const f32x4 w30 = *(const f32x4*)&W3l[0 * 16 + quad * 4];
        const f32x4 w31 = *(const f32x4*)&W3l[1 * 16 + quad * 4];
        const f32x4 w32 = *(const f32x4*)&W3l[2 * 16 + quad * 4];
        #pragma unroll
        for (int r = 0; r < 4; ++r) {
            s += fmaxf(c0[r], 0.f) * w30[r];
            s += fmaxf(c1[r], 0.f) * w31[r];
            s += fmaxf(c2[r], 0.f) * w32[r];
        }
        s += __shfl_xor(s, 16, 64);                // sum the 4 quads (full sum in every lane)
        s += __shfl_xor(s, 32, 64);
        if (quad == i) {                           // pv_q(quad=i) = poly for mt=wave+6i ✓
            // row m = mt*16 + l15 -> out[b0 + (m&7)][m>>3]
            out[(size_t)(b0 + (l15 & 7)) * 40 + 2 * mt + (l15 >> 3)] = s + b3v + pv_q;
        }
    };

    // ---------- prologue ----------
    prestage_u(0);
    __syncthreads();   // B1: B_lds + W2sz + W3l + u_sbuf[0] ready

    #pragma unroll
    for (int nt = 0; nt < 2; ++nt)
        #pragma unroll
        for (int ks = 0; ks < 8; ++ks)
            aW2[nt][ks] = *(const s16x8*)&B_lds[((nt * 8 + ks) * 64 + lane) * 8];

    pv_q = poly1(u_sbuf[0], mtqc * 16 + l15);   // poly for group 0
    prestage_u(1);
    __syncthreads();   // B2: aW2 fragment reads done -> safe to overwrite gtile[0]

    phase2(0);
    __syncthreads();   // B3: gtile[0] ready

    // ---------- main loop ----------
    // interval g: [issue u-loads g+2] [poly(g+1)->temp] P3(g) phase2(g+1) [commit u g+2] barrier
    for (int g = 0; g < NBG; ++g) {
        const int b0 = b0_block + g * TB;
        const unsigned short* gt = &gtile[g & 1][0];

        if (g + 2 < NBG) prestage_issue(g + 2);          // loads in flight across the interval

        float tq = 0.f;
        if (g + 1 < NBG)                                  // poly for g+1: independent VALU work
            tq = poly1(u_sbuf[(g + 1) & 1], mtqc * 16 + l15);

        #pragma unroll
        for (int i = 0; i < 4; ++i) {
            if (wave + WAVES * i >= 20) continue;         // wave-uniform guard (waves 2-5: 3 tiles)
            p3_tile(i, gt, b0);                           // consumes pv_q (group g)
        }

        if (g + 1 < NBG) {
            phase2(g + 1);                                // writes gtile[(g+1)&1] (opposite buffer)
            if (g + 2 < NBG) prestage_commit(g + 2);      // vmcnt + LDS write, latency already hidden
            pv_q = tq;                                    // pv reg now holds group g+1
            __syncthreads();                              // window barrier: gtile[(g+1)&1] ready
        }
    }
}

extern "C" void kernel_launch(void* const* d_in, const int* in_sizes, int n_in,
                              void* d_out, int out_size, void* d_ws, size_t ws_size,
                              hipStream_t stream) {
    // inputs: 0=t(unused), 1=u, 2=coeff, 3=W1, 4=b1, 5=W2, 6=b2, 7=W3, 8=b3
    const float* u     = (const float*)d_in[1];
    const float* coeff = (const float*)d_in[2];
    const float* W1    = (const float*)d_in[3];
    const float* b1    = (const float*)d_in[4];
    const float* W2    = (const float*)d_in[5];
    const float* b2    = (const float*)d_in[6];
    const float* W3    = (const float*)d_in[7];
    const float* b3    = (const float*)d_in[8];
    float* out = (float*)d_out;

    const int n_batch = in_sizes[1] / 40;            // 65536
    const int grid = n_batch / (TB * NBG);           // 512 blocks = one full 2-blocks/CU round
    lorenz96_fused<<<grid, NTHREADS, 0, stream>>>(u, coeff, W1, b1, W2, b2, W3, b3, out);
}

// Round 4
// 178.697 us; speedup vs baseline: 1.4223x; 1.4223x over previous
//
#include <hip/hip_runtime.h>
#include <hip/hip_bf16.h>

typedef short s16x8 __attribute__((ext_vector_type(8)));
typedef short s16x4 __attribute__((ext_vector_type(4)));
typedef float f32x4 __attribute__((ext_vector_type(4)));

#define TB 8            // batch elements per group
#define NBG 16          // groups per block; grid 512 = exactly 2 blocks/CU
#define HALO 46         // gtile positions per batch (pos -2 .. 43)
#define GSTRIDE 2216    // shorts per batch in gtile (8*odd: bank-decorrelated)
#define USTRIDE 50      // floats per batch in u_s halo
#define NT 3            // stage-2 N tiles (48 cols, >=37 zero-padded; k=240 = b2 row)
#define GT_SHORTS (TB * GSTRIDE)       // 17728 shorts = 35456 B per buffer

__device__ __forceinline__ unsigned short f2bf(float f) {
    unsigned int u = __float_as_uint(f);
    u += 0x7fff + ((u >> 16) & 1);   // RNE
    return (unsigned short)(u >> 16);
}

// packed f32x2 -> bf16x2 (v_cvt_pk_bf16_f32, RNE)
__device__ __forceinline__ unsigned int pk_bf16(float lo, float hi) {
    float2 f; f.x = lo; f.y = hi;
    __hip_bfloat162 h = __float22bfloat162_rn(f);
    union { __hip_bfloat162 b; unsigned int u; } c;
    c.b = h;
    return c.u;
}

// force a uniform value into SGPR
__device__ __forceinline__ float sload(const float* p) {
    return __uint_as_float(__builtin_amdgcn_readfirstlane(__float_as_uint(*p)));
}

// (256,2): combined VGPR+AGPR ~200/wave; occupancy >2 waves/SIMD is DEAD (R1: 256x3 spilled;
// R3: 384x3 spilled AND dropped to 1 block/CU -> 194us; true reg need ~200, LDS-streaming
// aW2 would saturate the LDS pipe). This round: ILP within 2 waves/SIMD — split each p3
// accumulator chain in half (6 independent MFMA chains vs 3; dependent-accumulate latency
// was exposed every K-step) + s_setprio around the MFMA cluster (cross-block wave drift).
// Guards: WRITE_SIZE == 10.24 MB (spill -> 20MB+), VGPR_Count <= ~150, LDS 74240.
__global__ __launch_bounds__(256, 2) void lorenz96_fused(
    const float* __restrict__ u,
    const float* __restrict__ coeff,
    const float* __restrict__ W1,
    const float* __restrict__ b1,
    const float* __restrict__ W2,
    const float* __restrict__ b2,
    const float* __restrict__ W3,
    const float* __restrict__ b3,
    float* __restrict__ out)
{
    // LDS: gtile 2x35456 (buf0 aliases W2 staging) + u_sbuf 3200 = 74112 B -> 2 blocks/CU
    __shared__ __align__(16) unsigned short gtile[2][GT_SHORTS];
    __shared__ __align__(16) float u_sbuf[2][TB * USTRIDE];   // u_s[b][k] = u[b][(k+36)%40]

    unsigned short* B_lds = &gtile[0][0];   // alias: consumed into regs before gtile[0] is written

    const int t    = threadIdx.x;
    const int lane = t & 63;
    const int wave = t >> 6;
    const int quad = lane >> 4;
    const int l15  = lane & 15;

    const int b0_block = blockIdx.x * (TB * NBG);

    // ---------- init 0a: W2 staging, pre-swizzled; k=240 carries b2 (bias row, B supplies 1.0) ----------
    // W2eff[o][k = tap*48 + c] = W2[o][c][tap]; lane holds [o = nt*16+l15][k = ks*32+quad*8+j]
    for (int g = t; g < NT * 8 * 64; g += 256) {
        int lg = g & 63;
        int ks = (g >> 6) & 7;
        int nt = g >> 9;
        int o  = nt * 16 + (lg & 15);
        int kb = ks * 32 + (lg >> 4) * 8;
        s16x8 pack = {0, 0, 0, 0, 0, 0, 0, 0};
        #pragma unroll
        for (int j = 0; j < 8; ++j) {
            int k = kb + j;
            if (o < 37) {
                if (k < 240) {
                    int c = k % 48, tap = k / 48;
                    pack[j] = (short)f2bf(W2[o * 240 + c * 5 + tap]);
                } else if (k == 240) {
                    pack[j] = (short)f2bf(b2[o]);
                }
            }
        }
        *(s16x8*)&B_lds[g * 8] = pack;
    }

    // ---------- init 0b: conv1 A-fragments (W1 + fused b1 at k=5) ----------
    // tiles: T0=ch0-15, T1=ch16-31, T2=ch32-47, T3 rows8-15=ch48-55, T4=ch56-71.
    // GLU in-lane: T1 rows8-15 x T3 rows8-15; T2 x T4 (same quad,reg).
    s16x8 aW1[5];
    {
        int chs[5];
        chs[0] = l15; chs[1] = 16 + l15; chs[2] = 32 + l15;
        chs[3] = (l15 >= 8) ? 40 + l15 : -1;
        chs[4] = 56 + l15;
        #pragma unroll
        for (int mt = 0; mt < 5; ++mt) {
            s16x8 a = {0, 0, 0, 0, 0, 0, 0, 0};
            int ch = chs[mt];
            if (quad == 0 && ch >= 0) {
                #pragma unroll
                for (int j = 0; j < 5; ++j) a[j] = (short)f2bf(W1[ch * 5 + j]);
                a[5] = (short)f2bf(b1[ch]);   // bias slot; B supplies 1.0 at k=5
            }
            aW1[mt] = a;
        }
    }

    // ---------- init 0c: epilogue constants (b2 folded into GEMM; only W3 left) ----------
    float w3v[NT][4];
    #pragma unroll
    for (int nt = 0; nt < NT; ++nt)
        #pragma unroll
        for (int r = 0; r < 4; ++r) {
            int o = nt * 16 + quad * 4 + r;
            w3v[nt][r] = (o < 37) ? W3[o] : 0.f;
        }
    const float b3v = sload(b3);
    float cf[18];
    #pragma unroll
    for (int i = 0; i < 18; ++i) cf[i] = sload(&coeff[i]);   // SGPR-resident

    // stage-2 A-fragments (declared before lambdas so they capture it)
    s16x8 aW2[NT][8];
    // poly term registers: pv_q = row of tile i=quad; pv_4 = row of tile i=4 (valid on quad 0)
    float pv_q = 0.f, pv_4 = 0.f;
    // T14 staging registers for the split prestage (static-indexed -> stay in VGPRs)
    float st_v0 = 0.f, st_v1 = 0.f;

    // ---------- helpers ----------
    auto prestage_u = [&](int grp) {   // prologue-only: full stage of group grp into u_sbuf[grp&1]
        for (int idx = t; idx < TB * USTRIDE; idx += 256) {
            int b = idx / USTRIDE, k = idx - b * USTRIDE;
            int gi = k + 36; gi -= (gi >= 40) ? 40 : 0; gi -= (gi >= 40) ? 40 : 0;
            u_sbuf[grp & 1][idx] = u[(size_t)(b0_block + grp * TB + b) * 40 + gi];
        }
    };

    auto prestage_issue = [&](int grp) {   // T14 part 1: issue global loads into regs
        {
            int idx = t;                                   // idx < 400 always (t < 256)
            int b = idx / USTRIDE, k = idx - b * USTRIDE;
            int gi = k + 36; gi -= (gi >= 40) ? 40 : 0; gi -= (gi >= 40) ? 40 : 0;
            st_v0 = u[(size_t)(b0_block + grp * TB + b) * 40 + gi];
        }
        if (t + 256 < TB * USTRIDE) {
            int idx = t + 256;
            int b = idx / USTRIDE, k = idx - b * USTRIDE;
            int gi = k + 36; gi -= (gi >= 40) ? 40 : 0; gi -= (gi >= 40) ? 40 : 0;
            st_v1 = u[(size_t)(b0_block + grp * TB + b) * 40 + gi];
        }
    };

    auto prestage_commit = [&](int grp) {  // T14 part 2: LDS writes (just before barrier)
        u_sbuf[grp & 1][t] = st_v0;
        if (t + 256 < TB * USTRIDE) u_sbuf[grp & 1][t + 256] = st_v1;
    };

    auto poly1 = [&](const float* u_s, int m) -> float {   // poly term for output row m
        int p = m >> 3, b = m & 7;
        const float* us = &u_s[b * USTRIDE + p];
        float um2 = us[2], um1 = us[3], u0 = us[4], up1 = us[5], up2 = us[6];
        return cf[0] + cf[1]*um2 + cf[2]*um1 + cf[3]*u0 + cf[4]*up1 + cf[5]*up2
             + cf[6]*um2*um2 + cf[7]*um1*um1 + cf[8]*u0*u0 + cf[9]*up1*up1 + cf[10]*up2*up2
             + cf[11]*um2*um1 + cf[12]*um1*u0 + cf[13]*u0*up1 + cf[14]*up1*up2
             + cf[15]*um2*u0 + cf[16]*um1*up1 + cf[17]*u0*up2;
    };

    auto phase2 = [&](int gi) {       // conv1 via MFMA + GLU -> gtile[gi&1]
        const float* u_s = u_sbuf[gi & 1];
        unsigned short* gt = &gtile[gi & 1][0];
        #pragma unroll
        for (int i = 0; i < 6; ++i) {
            const int ct = wave + 4 * i;               // col-tiles 0..22 live (cols 0..367)
            if (ct > 22) continue;                      // only wave3,i=5: cols 368+ are pad
            const int col = ct * 16 + l15;
            const int b = col & 7, h = col >> 3;        // h <= 45 < HALO always
            s16x8 bU = {0, 0, 0, 0, 0, 0, 0, 0};
            if (quad == 0) {                            // exec-masked: only 16 lanes touch LDS
                const float* us = &u_s[b * USTRIDE + h];   // taps u[(h-4+j)%40], j=0..4
                union { s16x8 v; unsigned int w[4]; } bu;
                bu.w[0] = pk_bf16(us[0], us[1]);
                bu.w[1] = pk_bf16(us[2], us[3]);
                bu.w[2] = pk_bf16(us[4], 1.0f);            // 1.0 -> bias slot k=5
                bu.w[3] = 0;
                bU = bu.v;
            }
            f32x4 a0 = {0.f,0.f,0.f,0.f}, a1 = a0, a2 = a0, a3 = a0, a4 = a0;
            a0 = __builtin_amdgcn_mfma_f32_16x16x32_bf16(aW1[0], bU, a0, 0, 0, 0);
            a1 = __builtin_amdgcn_mfma_f32_16x16x32_bf16(aW1[1], bU, a1, 0, 0, 0);
            a2 = __builtin_amdgcn_mfma_f32_16x16x32_bf16(aW1[2], bU, a2, 0, 0, 0);
            a3 = __builtin_amdgcn_mfma_f32_16x16x32_bf16(aW1[3], bU, a3, 0, 0, 0);
            a4 = __builtin_amdgcn_mfma_f32_16x16x32_bf16(aW1[4], bU, a4, 0, 0, 0);
            float v0[4], v1[4], v2[4];
            #pragma unroll
            for (int r = 0; r < 4; ++r) {
                v0[r] = fmaxf(a0[r], 0.f);
                v1[r] = fmaxf(a1[r], 0.f);
                if (quad >= 2) v1[r] *= fmaxf(a3[r], 0.f);          // ch24-31 gate
                v2[r] = fmaxf(a2[r], 0.f) * fmaxf(a4[r], 0.f);      // ch32-47 gate
            }
            union { s16x4 v; unsigned int w[2]; } w0, w1, w2;
            w0.w[0] = pk_bf16(v0[0], v0[1]); w0.w[1] = pk_bf16(v0[2], v0[3]);
            w1.w[0] = pk_bf16(v1[0], v1[1]); w1.w[1] = pk_bf16(v1[2], v1[3]);
            w2.w[0] = pk_bf16(v2[0], v2[1]); w2.w[1] = pk_bf16(v2[2], v2[3]);
            unsigned short* gp = &gt[b * GSTRIDE + h * 48 + quad * 4];
            *(s16x4*)(gp)      = w0.v;
            *(s16x4*)(gp + 16) = w1.v;
            *(s16x4*)(gp + 32) = w2.v;
        }
    };

    // P3 tile i: stage-2 GEMM on M-tile (wave+4i) + fused relu/W3 epilogue -> out.
    // Split accumulators: cXa covers ks 0-3, cXb covers ks 4-7 -> 6 independent MFMA
    // chains (vs 3), hiding the dependent-accumulate latency. Summed in fp32 at epilogue.
    auto p3_tile = [&](int i, const unsigned short* gt, int b0) {
        const int mt = wave + 4 * i;               // 20 M-tiles (320 G-rows)
        const int m  = mt * 16 + l15;
        const int p  = m >> 3, b = m & 7;
        const unsigned short* gbase = &gt[b * GSTRIDE + p * 48 + quad * 8];
        s16x8 bg[8];
        #pragma unroll
        for (int ks = 0; ks < 8; ++ks) bg[ks] = *(const s16x8*)(gbase + ks * 32);
        {   // bias row: B[k=240][*] must read 1.0 (k=240 <-> ks=7, quad=2, j=0)
            s16x8 b7 = bg[7];
            if (quad == 2) b7[0] = (short)0x3F80;
            bg[7] = b7;
        }
        f32x4 c0a = {0.f,0.f,0.f,0.f}, c1a = c0a, c2a = c0a;
        f32x4 c0b = c0a, c1b = c0a, c2b = c0a;
        __builtin_amdgcn_s_setprio(1);
        #pragma unroll
        for (int j = 0; j < 4; ++j) {
            c0a = __builtin_amdgcn_mfma_f32_16x16x32_bf16(aW2[0][j],     bg[j],     c0a, 0, 0, 0);
            c1a = __builtin_amdgcn_mfma_f32_16x16x32_bf16(aW2[1][j],     bg[j],     c1a, 0, 0, 0);
            c2a = __builtin_amdgcn_mfma_f32_16x16x32_bf16(aW2[2][j],     bg[j],     c2a, 0, 0, 0);
            c0b = __builtin_amdgcn_mfma_f32_16x16x32_bf16(aW2[0][4 + j], bg[4 + j], c0b, 0, 0, 0);
            c1b = __builtin_amdgcn_mfma_f32_16x16x32_bf16(aW2[1][4 + j], bg[4 + j], c1b, 0, 0, 0);
            c2b = __builtin_amdgcn_mfma_f32_16x16x32_bf16(aW2[2][4 + j], bg[4 + j], c2b, 0, 0, 0);
        }
        __builtin_amdgcn_s_setprio(0);
        float s = 0.f;
        #pragma unroll
        for (int r = 0; r < 4; ++r) {
            s += fmaxf(c0a[r] + c0b[r], 0.f) * w3v[0][r];
            s += fmaxf(c1a[r] + c1b[r], 0.f) * w3v[1][r];
            s += fmaxf(c2a[r] + c2b[r], 0.f) * w3v[2][r];
        }
        s += __shfl_xor(s, 16, 64);                // sum the 4 quads (full sum in every lane)
        s += __shfl_xor(s, 32, 64);
        const float pv = (i < 4) ? pv_q : pv_4;
        const bool  st = (i < 4) ? (quad == i) : (quad == 0);
        if (st) {
            // row m = mt*16 + l15 -> out[b0 + (m&7)][m>>3]
            out[(size_t)(b0 + (l15 & 7)) * 40 + 2 * mt + (l15 >> 3)] = s + b3v + pv;
        }
    };

    // ---------- prologue ----------
    prestage_u(0);
    __syncthreads();   // B1: B_lds + u_sbuf[0] ready

    #pragma unroll
    for (int nt = 0; nt < NT; ++nt)
        #pragma unroll
        for (int ks = 0; ks < 8; ++ks)
            aW2[nt][ks] = *(const s16x8*)&B_lds[((nt * 8 + ks) * 64 + lane) * 8];

    {   // poly for group 0
        const float* u_s = u_sbuf[0];
        pv_q = poly1(u_s, (wave + 4 * quad) * 16 + l15);
        pv_4 = poly1(u_s, (wave + 16) * 16 + l15);
    }
    prestage_u(1);
    __syncthreads();   // B2: aW2 fragment reads done -> safe to overwrite gtile[0]

    phase2(0);
    __syncthreads();   // B3: gtile[0] ready

    // ---------- main loop ----------
    // interval g: [issue u-loads g+2] [poly(g+1)->temps] P3(g) phase2(g+1) [commit u g+2] barrier
    // u_sbuf[g&1] is dead at interval start (its readers finished before the last barrier),
    // so the g+2 stage ((g+2)&1 == g&1) can span the whole interval: HBM latency hides
    // under P3+phase2 instead of sitting exposed before the barrier (T14).
    for (int g = 0; g < NBG; ++g) {
        const int b0 = b0_block + g * TB;
        const unsigned short* gt = &gtile[g & 1][0];

        if (g + 2 < NBG) prestage_issue(g + 2);          // loads in flight across the interval

        float tq = 0.f, t4 = 0.f;
        if (g + 1 < NBG) {                                // poly for g+1: independent VALU work
            const float* u_s = u_sbuf[(g + 1) & 1];       // ready since previous interval
            tq = poly1(u_s, (wave + 4 * quad) * 16 + l15);
            t4 = poly1(u_s, (wave + 16) * 16 + l15);
        }

        #pragma unroll
        for (int i = 0; i < 5; ++i) p3_tile(i, gt, b0);   // consumes pv (group g)

        if (g + 1 < NBG) {
            phase2(g + 1);                                // writes gtile[(g+1)&1] (opposite buffer)
            if (g + 2 < NBG) prestage_commit(g + 2);      // vmcnt + LDS write, latency already hidden
            pv_q = tq; pv_4 = t4;                         // pv regs now hold group g+1
            __syncthreads();                              // window barrier: gtile[(g+1)&1] ready
        }
    }
}

extern "C" void kernel_launch(void* const* d_in, const int* in_sizes, int n_in,
                              void* d_out, int out_size, void* d_ws, size_t ws_size,
                              hipStream_t stream) {
    // inputs: 0=t(unused), 1=u, 2=coeff, 3=W1, 4=b1, 5=W2, 6=b2, 7=W3, 8=b3
    const float* u     = (const float*)d_in[1];
    const float* coeff = (const float*)d_in[2];
    const float* W1    = (const float*)d_in[3];
    const float* b1    = (const float*)d_in[4];
    const float* W2    = (const float*)d_in[5];
    const float* b2    = (const float*)d_in[6];
    const float* W3    = (const float*)d_in[7];
    const float* b3    = (const float*)d_in[8];
    float* out = (float*)d_out;

    const int n_batch = in_sizes[1] / 40;            // 65536
    const int grid = n_batch / (TB * NBG);           // 512 blocks = one full 2-blocks/CU round
    lorenz96_fused<<<grid, 256, 0, stream>>>(u, coeff, W1, b1, W2, b2, W3, b3, out);
}